// Round 5
// baseline (220.239 us; speedup 1.0000x reference)
//
#include <hip/hip_runtime.h>
#include <stdint.h>

// y[b,r] = sum_t x[b, idx[r,t]] * w[r,t] - bias[r]
// fp32 x (1024x4096), fp32 w (8192x32), fp32 bias (8192), int32 idx (8192x32), fp32 out (1024x8192)

#define IN_DIM   4096
#define OUT_DIM  8192
#define BATCH    1024
#define NACT     32
#define R_TILE   64
#define B_TILE   128
#define N_RTILES (OUT_DIM / R_TILE)           // 128 row-tiles per chunk
#define N_CHUNK  (BATCH / B_TILE)             // 8 batch chunks
#define CHUNK_WORDS (IN_DIM * (B_TILE / 2))   // 1 MB per chunk (bf16 pairs)
#define CNT_BYTES 1024                        // 8 counters, 128B apart

typedef float f4v __attribute__((ext_vector_type(4)));

__device__ __forceinline__ float bf2f(ushort u) {
    union { uint32_t i; float f; } v; v.i = ((uint32_t)u) << 16; return v.f;
}
__device__ __forceinline__ ushort f2bf(float f) {
    union { float f; uint32_t i; } v; v.f = f;
    uint32_t b = v.i + 0x7fffu + ((v.i >> 16) & 1u);   // RNE
    return (ushort)(b >> 16);
}

// ---- x (1024 x 4096 fp32) -> xT chunk-major [chunk][c][b%128] bf16; also zero claim counters ----
__global__ __launch_bounds__(256) void transpose_to_bf16(const float* __restrict__ x,
                                                         uint32_t* __restrict__ xT32,
                                                         int* __restrict__ cnt) {
    if (cnt && blockIdx.x == 0 && blockIdx.y == 0 && threadIdx.x < (CNT_BYTES / 4))
        cnt[threadIdx.x] = 0;
    __shared__ float tile[64][65];
    const int tx = threadIdx.x & 63, ty0 = threadIdx.x >> 6;
    const int c0 = blockIdx.x * 64, b0 = blockIdx.y * 64;
#pragma unroll
    for (int k = 0; k < 16; ++k) {
        int b = ty0 + k * 4;
        tile[b][tx] = x[(size_t)(b0 + b) * IN_DIM + c0 + tx];
    }
    __syncthreads();
    const int bchunk  = b0 >> 7;
    const int b_local = (b0 & 127) >> 1;
    uint32_t* dst = xT32 + (size_t)bchunk * CHUNK_WORDS + b_local;
#pragma unroll
    for (int k = 0; k < 8; ++k) {
        int lin = k * 256 + threadIdx.x;
        int c = lin >> 5, bp = lin & 31;
        ushort u0 = f2bf(tile[2 * bp][c]);
        ushort u1 = f2bf(tile[2 * bp + 1][c]);
        dst[(size_t)(c0 + c) * (B_TILE / 2) + bp] = u0 | ((uint32_t)u1 << 16);
    }
}

// MODE: 0 = direct fp32 (no ws), 1 = xT static chunk (bid&7), 2 = xT XCD-pinned (atomic claim)
template <int MODE>
__global__ __launch_bounds__(256, 4) void sparse_mm(const void*  __restrict__ xsrc,
                                                    const int*   __restrict__ idx,
                                                    const float* __restrict__ w,
                                                    const float* __restrict__ bias,
                                                    float*       __restrict__ out,
                                                    int*         __restrict__ cnt) {
    __shared__ float s_out[B_TILE][R_TILE + 1];   // 33.3 KB
    __shared__ int s_tile;

    const int tid = threadIdx.x, wave = tid >> 6, lane = tid & 63;

    int bchunk, rtile;
    if (MODE == 2) {
        // claim a tile on THIS physical XCD: chunk = actual XCC_ID -> chunk stays L2-resident.
        // Counting argument: a block can fail all 8 probes only if >=1024 successful claims
        // already happened -> impossible with 1023 other blocks -> every tile claimed once.
        if (tid == 0) {
            uint32_t xcc;
            asm volatile("s_getreg_b32 %0, hwreg(HW_REG_XCC_ID)" : "=s"(xcc));
            int t = -1;
#pragma unroll
            for (int j = 0; j < N_CHUNK; ++j) {
                int c = (int)((xcc + j) & (N_CHUNK - 1));
                int v = atomicAdd(&cnt[c * 32], 1);
                if (v < N_RTILES) { t = c * N_RTILES + v; break; }
            }
            s_tile = t;
        }
        __syncthreads();
        if (s_tile < 0) return;
        bchunk = s_tile >> 7;
        rtile  = s_tile & (N_RTILES - 1);
    } else {
        bchunk = blockIdx.x & (N_CHUNK - 1);
        rtile  = blockIdx.x >> 3;
    }
    const int r0 = rtile * R_TILE, b0 = bchunk * B_TILE;

    // detect int64-layout idx (all odd dwords zero); uniform branch
    const uint32_t* gi = (const uint32_t*)idx;
    const bool idx64 = ((gi[1] | gi[3] | gi[5] | gi[7] | gi[9] | gi[11] | gi[13] | gi[15]) == 0u);

    const uint32_t* xb = (const uint32_t*)xsrc + (size_t)bchunk * CHUNK_WORDS + lane;
    const float*    xf = (const float*)xsrc;

#pragma unroll 1
    for (int g = 0; g < 4; ++g) {
        const int rl = wave * 16 + g * 4;
        const int rb = r0 + rl;
        float a0[4], a1[4];
#pragma unroll
        for (int k = 0; k < 4; ++k) { float bv = bias[rb + k]; a0[k] = -bv; a1[k] = -bv; }

#pragma unroll
        for (int k = 0; k < 4; ++k) {
            int ci[NACT];
            if (!idx64) {
                const int4* ir = (const int4*)(idx + (size_t)(rb + k) * NACT);
#pragma unroll
                for (int q = 0; q < 8; ++q) {
                    int4 ii = ir[q];
                    ci[4 * q] = ii.x; ci[4 * q + 1] = ii.y; ci[4 * q + 2] = ii.z; ci[4 * q + 3] = ii.w;
                }
            } else {
                const int4* ir = (const int4*)((const char*)idx + (size_t)(rb + k) * NACT * 8);
#pragma unroll
                for (int q = 0; q < 16; ++q) {
                    int4 ii = ir[q];
                    ci[2 * q] = ii.x; ci[2 * q + 1] = ii.z;
                }
            }
            const float4* wr = (const float4*)(w + (size_t)(rb + k) * NACT);
#pragma unroll
            for (int q = 0; q < 8; ++q) {
                float4 wf = wr[q];
                float wv[4] = {wf.x, wf.y, wf.z, wf.w};
#pragma unroll
                for (int u = 0; u < 4; ++u) {
                    const int c = ci[4 * q + u];
                    if (MODE != 0) {
                        uint32_t v = xb[(uint32_t)c << 6];   // c*64 words; 256B/wave coalesced
                        a0[k] = fmaf(bf2f((ushort)(v & 0xffffu)), wv[u], a0[k]);
                        a1[k] = fmaf(bf2f((ushort)(v >> 16)),     wv[u], a1[k]);
                    } else {
                        float e0 = xf[(size_t)(b0 + 2 * lane)     * IN_DIM + c];
                        float e1 = xf[(size_t)(b0 + 2 * lane + 1) * IN_DIM + c];
                        a0[k] = fmaf(e0, wv[u], a0[k]);
                        a1[k] = fmaf(e1, wv[u], a1[k]);
                    }
                }
            }
        }
#pragma unroll
        for (int k = 0; k < 4; ++k) {
            s_out[2 * lane    ][rl + k] = a0[k];
            s_out[2 * lane + 1][rl + k] = a1[k];
        }
    }
    __syncthreads();

    // coalesced NT epilogue: wave = 4 batches x 256B contiguous (full lines)
#pragma unroll
    for (int it = 0; it < 8; ++it) {
        int lin = it * 256 + tid;
        int b  = lin >> 4;
        int rp = lin & 15;
        f4v v;
        v.x = s_out[b][4 * rp + 0];
        v.y = s_out[b][4 * rp + 1];
        v.z = s_out[b][4 * rp + 2];
        v.w = s_out[b][4 * rp + 3];
        f4v* p = (f4v*)&out[(size_t)(b0 + b) * OUT_DIM + r0 + 4 * rp];
        __builtin_nontemporal_store(v, p);
    }
}

extern "C" void kernel_launch(void* const* d_in, const int* in_sizes, int n_in,
                              void* d_out, int out_size, void* d_ws, size_t ws_size,
                              hipStream_t stream) {
    const float* x    = (const float*)d_in[0];
    const float* wk   = (const float*)d_in[1];
    const float* bias = (const float*)d_in[2];
    const int*   idx  = (const int*)d_in[3];
    float*       out  = (float*)d_out;

    const size_t xT_bytes = (size_t)IN_DIM * BATCH * 2;        // 8 MB
    const int nblocks = N_RTILES * N_CHUNK;                    // 1024

    if (ws_size >= xT_bytes + CNT_BYTES) {
        uint32_t* xT32 = (uint32_t*)d_ws;
        int*      cnt  = (int*)((char*)d_ws + xT_bytes);       // counters AFTER xT
        transpose_to_bf16<<<dim3(IN_DIM / 64, BATCH / 64), 256, 0, stream>>>(x, xT32, cnt);
        sparse_mm<2><<<nblocks, 256, 0, stream>>>((const void*)xT32, idx, wk, bias, out, cnt);
    } else if (ws_size >= xT_bytes) {
        uint32_t* xT32 = (uint32_t*)d_ws;
        transpose_to_bf16<<<dim3(IN_DIM / 64, BATCH / 64), 256, 0, stream>>>(x, xT32, nullptr);
        sparse_mm<1><<<nblocks, 256, 0, stream>>>((const void*)xT32, idx, wk, bias, out, nullptr);
    } else {
        sparse_mm<0><<<nblocks, 256, 0, stream>>>((const void*)x, idx, wk, bias, out, nullptr);
    }
}

// Round 6
// 50.050 us; speedup vs baseline: 4.4004x; 4.4004x over previous
//
#include <hip/hip_runtime.h>
#include <stdint.h>

// y[b,r] = sum_t x[b, idx[r,t]] * w[r,t] - bias[r]
// fp32 x (1024x4096), fp32 w (8192x32), fp32 bias (8192), int32 idx (8192x32), fp32 out (1024x8192)
//
// Strategy: gather from LDS (deterministic), not L2 (3 rounds showed ~50% miss
// regardless of locality scheme). x is pre-transposed to bf16 in per-8-batch
// slices of 64 KB; each block stages one slice in LDS and serves all gathers
// with ds_read_b64. idx/w pre-transposed to [t][r] for coalesced streaming.

#define IN_DIM   4096
#define OUT_DIM  8192
#define BATCH    1024
#define NACT     32

#define B_SLICE      8                        // batches per LDS slice
#define N_SLICE      (BATCH / B_SLICE)        // 128
#define SLICE_WORDS  (IN_DIM * (B_SLICE / 2)) // 16384 words = 64 KB
#define R_PER_BLK    1024
#define N_RSPLIT     (OUT_DIM / R_PER_BLK)    // 8
#define MAIN_THREADS 512

__device__ __forceinline__ ushort f2bf(float f) {
    union { float f; uint32_t i; } v; v.f = f;
    uint32_t b = v.i + 0x7fffu + ((v.i >> 16) & 1u);   // RNE
    return (ushort)(b >> 16);
}
__device__ __forceinline__ float blo(uint32_t v) {
    union { uint32_t i; float f; } u; u.i = v << 16; return u.f;
}
__device__ __forceinline__ float bhi(uint32_t v) {
    union { uint32_t i; float f; } u; u.i = v & 0xffff0000u; return u.f;
}

// ---- x (1024x4096 fp32) -> xTs [slice=b/8][c][bp=(b%8)/2] bf16-pair words ----
__global__ __launch_bounds__(256) void x_to_sliced_bf16(const float* __restrict__ x,
                                                        uint32_t* __restrict__ xTs) {
    __shared__ float tile[64][65];
    const int tid = threadIdx.x;
    const int c0 = blockIdx.x * 64, b0 = blockIdx.y * 64;
    const int tx = tid & 63, ty0 = tid >> 6;
#pragma unroll
    for (int k = 0; k < 16; ++k) {
        int b = ty0 + k * 4;
        tile[b][tx] = x[(size_t)(b0 + b) * IN_DIM + c0 + tx];
    }
    __syncthreads();
#pragma unroll
    for (int k = 0; k < 8; ++k) {
        int lin = k * 256 + tid;            // 0..2047 = 8 sl x 64 c x 4 bp
        int bp = lin & 3;
        int c  = (lin >> 2) & 63;
        int sl = lin >> 8;                  // 0..7 (uniform per wave)
        ushort u0 = f2bf(tile[sl * 8 + 2 * bp    ][c]);
        ushort u1 = f2bf(tile[sl * 8 + 2 * bp + 1][c]);
        // per-wave: 64 consecutive words = 256B contiguous store
        xTs[(size_t)((b0 >> 3) + sl) * SLICE_WORDS + (size_t)(c0 + c) * 4 + bp] =
            u0 | ((uint32_t)u1 << 16);
    }
}

// ---- idx/w (8192x32, row-major) -> idxT/wT (32x8192) ----
__global__ __launch_bounds__(256) void iw_transpose(const int* __restrict__ idx,
                                                    const float* __restrict__ w,
                                                    int* __restrict__ idxT,
                                                    float* __restrict__ wT) {
    __shared__ int   si[64][33];
    __shared__ float sw[64][33];
    const int tid = threadIdx.x;
    const int r0 = blockIdx.x * 64;
    // int64-layout sniff (odd dwords all zero) — uniform branch
    const uint32_t* gi = (const uint32_t*)idx;
    const bool idx64 = ((gi[1] | gi[3] | gi[5] | gi[7] | gi[9] | gi[11] | gi[13] | gi[15]) == 0u);
#pragma unroll
    for (int k = 0; k < 8; ++k) {
        int lin = k * 256 + tid;            // 2048 = 64 rows x 32 t
        int row = lin >> 5, t = lin & 31;
        int v;
        if (!idx64) v = idx[(size_t)(r0 + row) * NACT + t];
        else        v = idx[((size_t)(r0 + row) * NACT + t) * 2];
        si[row][t] = v;
        sw[row][t] = w[(size_t)(r0 + row) * NACT + t];
    }
    __syncthreads();
#pragma unroll
    for (int k = 0; k < 8; ++k) {
        int lin = k * 256 + tid;
        int t = lin >> 6, row = lin & 63;
        idxT[(size_t)t * OUT_DIM + r0 + row] = si[row][t];
        wT  [(size_t)t * OUT_DIM + r0 + row] = sw[row][t];
    }
}

// ---- main: block = 8-batch slice (64 KB LDS) x 1024 rows; all gathers via LDS ----
__global__ __launch_bounds__(MAIN_THREADS) void lds_gather(const uint32_t* __restrict__ xTs,
                                                           const int* __restrict__ idxT,
                                                           const float* __restrict__ wT,
                                                           const float* __restrict__ bias,
                                                           float* __restrict__ out) {
    __shared__ uint32_t s_x[SLICE_WORDS];   // 64 KB -> 2 blocks/CU
    const int tid = threadIdx.x;
    const int slice  = blockIdx.x & (N_SLICE - 1);
    const int rsplit = blockIdx.x >> 7;     // consecutive blocks share rsplit's idx/w range
    const int b0  = slice * B_SLICE;
    const int r0g = rsplit * R_PER_BLK;

    { // stage the 64 KB slice: linear copy, conflict-free ds_write_b128
        const uint4* g = (const uint4*)(xTs + (size_t)slice * SLICE_WORDS);
        uint4* s = (uint4*)s_x;
#pragma unroll
        for (int it = 0; it < 8; ++it) s[it * MAIN_THREADS + tid] = g[it * MAIN_THREADS + tid];
    }
    __syncthreads();

    const int wv = tid >> 6, lane = tid & 63;
    const int rsub = lane >> 1, wl = lane & 1;     // wave = 32 rows x 2 half-slices
    const uint32_t loff = (uint32_t)wl * 8u;       // byte offset within 16B c-row

#pragma unroll 1
    for (int rg = 0; rg < 4; ++rg) {
        const int r = r0g + (wv * 4 + rg) * 32 + rsub;
        float a0 = 0.f, a1 = 0.f, a2 = 0.f, a3 = 0.f;
        const int*   ip = idxT + r;
        const float* wp = wT + r;
#pragma unroll 8
        for (int t = 0; t < NACT; ++t) {
            const int   c  = ip[(size_t)t * OUT_DIM];   // coalesced 128B/wave
            const float wg = wp[(size_t)t * OUT_DIM];
            uint2 v = *(const uint2*)((const char*)s_x + (((uint32_t)c) << 4) + loff);
            a0 = fmaf(blo(v.x), wg, a0);
            a1 = fmaf(bhi(v.x), wg, a1);
            a2 = fmaf(blo(v.y), wg, a2);
            a3 = fmaf(bhi(v.y), wg, a3);
        }
        const float bv = bias[r];
        // stores: per instr = 2 x 128B full-line segments (rsub consecutive)
        const size_t ob = (size_t)(b0 + wl * 4) * OUT_DIM + r;
        out[ob              ] = a0 - bv;
        out[ob +     OUT_DIM] = a1 - bv;
        out[ob + 2 * OUT_DIM] = a2 - bv;
        out[ob + 3 * OUT_DIM] = a3 - bv;
    }
}

// ---- insurance fallback (ws too small): one thread per output ----
__global__ __launch_bounds__(256) void direct_gather(const float* __restrict__ x,
                                                     const int* __restrict__ idx,
                                                     const float* __restrict__ w,
                                                     const float* __restrict__ bias,
                                                     float* __restrict__ out) {
    const uint32_t* gi = (const uint32_t*)idx;
    const bool idx64 = ((gi[1] | gi[3] | gi[5] | gi[7] | gi[9] | gi[11] | gi[13] | gi[15]) == 0u);
    int o = blockIdx.x * 256 + threadIdx.x;
    int b = o >> 13, r = o & (OUT_DIM - 1);
    float acc = 0.f;
    const float* xb = x + (size_t)b * IN_DIM;
    for (int t = 0; t < NACT; ++t) {
        int c = idx64 ? idx[((size_t)r * NACT + t) * 2] : idx[(size_t)r * NACT + t];
        acc = fmaf(xb[c], w[(size_t)r * NACT + t], acc);
    }
    out[(size_t)b * OUT_DIM + r] = acc - bias[r];
}

extern "C" void kernel_launch(void* const* d_in, const int* in_sizes, int n_in,
                              void* d_out, int out_size, void* d_ws, size_t ws_size,
                              hipStream_t stream) {
    const float* x    = (const float*)d_in[0];
    const float* wk   = (const float*)d_in[1];
    const float* bias = (const float*)d_in[2];
    const int*   idx  = (const int*)d_in[3];
    float*       out  = (float*)d_out;

    const size_t xTs_bytes = (size_t)N_SLICE * SLICE_WORDS * 4;   // 8 MB
    const size_t idxT_bytes = (size_t)NACT * OUT_DIM * 4;         // 1 MB
    const size_t need = xTs_bytes + 2 * idxT_bytes;               // 10 MB

    if (ws_size >= need) {
        uint32_t* xTs  = (uint32_t*)d_ws;
        int*      idxT = (int*)((char*)d_ws + xTs_bytes);
        float*    wT   = (float*)((char*)d_ws + xTs_bytes + idxT_bytes);
        x_to_sliced_bf16<<<dim3(IN_DIM / 64, BATCH / 64), 256, 0, stream>>>(x, xTs);
        iw_transpose<<<OUT_DIM / 64, 256, 0, stream>>>(idx, wk, idxT, wT);
        lds_gather<<<N_SLICE * N_RSPLIT, MAIN_THREADS, 0, stream>>>(xTs, idxT, wT, bias, out);
    } else {
        direct_gather<<<(BATCH * OUT_DIM) / 256, 256, 0, stream>>>(x, idx, wk, bias, out);
    }
}